// Round 4
// baseline (249.504 us; speedup 1.0000x reference)
//
#include <hip/hip_runtime.h>

// PoolingNms fused: 3 chained pool/unpool (k=3,5,6) on 16x1x1080x1920 fp32.
// Unpool puts each window max back at its own position -> after stage 1 the
// tensor is sparse (<=1 survivor per 3x3 cell, at its original location);
// stages 2/3 are pure filters over the survivor set. lcm(3,5,6)=30 divides
// 1080 and 1920 -> every 30x30 supertile is fully independent.
//
// R4: one WAVE owns one 30x30 supertile end-to-end (R1/R2/R3 all plateaued
// at ~92us, 1.4 TB/s logical read BW = latency-bound at 35% occupancy).
// Per-wave: direct global window loads -> survivor table -> 5x5 filter ->
// 6x6 filter -> scatter into per-wave 3.6KB LDS compose tile -> one
// coalesced float2 store. LDS 18.3KB/block -> 8 blocks/CU = 32 waves/CU.
// Tie-break: packed pos (r<<5)|c ascending == row-major first-occurrence ==
// jnp.argmax, bit-exact (values >= 0; strict '>' scan).

#define IMG_H 1080
#define IMG_W 1920
#define NT 256

__global__ __launch_bounds__(NT) void pooling_nms_kernel(
    const float* __restrict__ x, float* __restrict__ out) {
    __shared__ float comp[4][900];  // per-wave 30x30 compose tile (14.4 KB)
    __shared__ float sv[4][100];    // per-wave stage-1 survivor values
    __shared__ int   sp[4][100];    // packed (r<<5)|c, supertile-local
    __shared__ float w5v[4][36];    // per-wave 5x5 winners
    __shared__ int   w5p[4][36];

    const int t = threadIdx.x;
    const int w = t >> 6;    // wave id 0..3
    const int ln = t & 63;   // lane

    const int stc = blockIdx.x * 4 + w;  // supertile col 0..63
    const int str = blockIdx.y;          // supertile row 0..35
    const size_t base = (size_t)blockIdx.z * ((size_t)IMG_H * IMG_W) +
                        (size_t)str * 30 * IMG_W + (size_t)stc * 30;
    const float* src = x + base;
    float* dst = out + base;

    // ---- Phase 0: zero this wave's compose tile (float4, 225 per wave).
    float4* c4 = reinterpret_cast<float4*>(comp[w]);
    for (int i = ln; i < 225; i += 64) c4[i] = make_float4(0.f, 0.f, 0.f, 0.f);

    // ---- Phase 1: stage-1 (k=3). 100 windows per supertile; lane ln handles
    // window ln and (if ln<36) window 64+ln. Reads go straight from global.
#pragma unroll
    for (int b = 0; b < 2; ++b) {
        const int win = b * 64 + ln;
        if (win < 100) {
            const int wr = win / 10, wc = win - wr * 10;
            const float* p = src + (size_t)(wr * 3) * IMG_W + wc * 3;
            float mx = -1.0f;
            int am = 0;
#pragma unroll
            for (int r = 0; r < 3; ++r) {
                const float v0 = p[(size_t)r * IMG_W + 0];
                const float v1 = p[(size_t)r * IMG_W + 1];
                const float v2 = p[(size_t)r * IMG_W + 2];
                const int rr = wr * 3 + r, cc = wc * 3;
                if (v0 > mx) { mx = v0; am = (rr << 5) | cc; }
                if (v1 > mx) { mx = v1; am = (rr << 5) | (cc + 1); }
                if (v2 > mx) { mx = v2; am = (rr << 5) | (cc + 2); }
            }
            sv[w][win] = mx;
            sp[w][win] = am;
        }
    }
    __syncthreads();

    // ---- Phase 2: stage-2 (k=5). 36 cells/supertile, lanes 0..35.
    if (ln < 36) {
        const int a = ln / 6, b = ln - (ln / 6) * 6;
        const int rlo = (5 * a) / 3, rhi = (5 * a + 4) / 3;
        const int clo = (5 * b) / 3, chi = (5 * b + 4) / 3;
        float bv = -1.0f;
        int bp = 0x7FFFFFFF;
        for (int r3 = rlo; r3 <= rhi; ++r3)
            for (int c3 = clo; c3 <= chi; ++c3) {
                const int idx = r3 * 10 + c3;
                const float v = sv[w][idx];
                const int p = sp[w][idx];
                const int r = p >> 5, c = p & 31;
                const bool in =
                    ((unsigned)(r - 5 * a) < 5u) & ((unsigned)(c - 5 * b) < 5u);
                if (in && (v > bv || (v == bv && p < bp))) { bv = v; bp = p; }
            }
        w5v[w][ln] = bv;  // -1 if cell empty
        w5p[w][ln] = bp;
    }
    __syncthreads();

    // ---- Phase 3: stage-3 (k=6). 25 cells/supertile, lanes 0..24; exactly
    // 4 candidate 5-cells each; winners scatter into the compose tile.
    if (ln < 25) {
        const int a = ln / 5, b = ln - (ln / 5) * 5;
        const int rlo = (6 * a) / 5, clo = (6 * b) / 5;
        float bv = -1.0f;
        int bp = 0x7FFFFFFF;
#pragma unroll
        for (int dr = 0; dr < 2; ++dr)
#pragma unroll
            for (int dc = 0; dc < 2; ++dc) {
                const int idx = (rlo + dr) * 6 + (clo + dc);
                const float v = w5v[w][idx];
                const int p = w5p[w][idx];
                const int r = p >> 5, c = p & 31;
                const bool in = (v >= 0.0f) &
                                ((unsigned)(r - 6 * a) < 6u) &
                                ((unsigned)(c - 6 * b) < 6u);
                if (in && (v > bv || (v == bv && p < bp))) { bv = v; bp = p; }
            }
        if (bv >= 0.0f) comp[w][(bp >> 5) * 30 + (bp & 31)] = bv;
    }
    __syncthreads();

    // ---- Phase 4: store compose tile, coalesced float2 (rows are 120 B,
    // global offsets always 8B-aligned: base cols are multiples of 30).
    const float2* c2 = reinterpret_cast<const float2*>(comp[w]);
    for (int i = ln; i < 450; i += 64) {
        const int r = i / 15, cc = i - r * 15;
        *reinterpret_cast<float2*>(dst + (size_t)r * IMG_W + cc * 2) = c2[i];
    }
}

extern "C" void kernel_launch(void* const* d_in, const int* in_sizes, int n_in,
                              void* d_out, int out_size, void* d_ws, size_t ws_size,
                              hipStream_t stream) {
    const float* x = (const float*)d_in[0];
    float* out = (float*)d_out;
    dim3 grid(IMG_W / 120, IMG_H / 30, 16);  // 16 x 36 x 16 = 9216 blocks
    pooling_nms_kernel<<<grid, NT, 0, stream>>>(x, out);
}